// Round 1
// baseline (638.937 us; speedup 1.0000x reference)
//
#include <hip/hip_runtime.h>
#include <math.h>

#define CH  256
#define SPA 4096                  // 64*64 spatial
#define BB  16
#define PLANE (BB * CH * SPA)     // 16777216 elements per [B,C,H,W] tensor

// ---------------- Kernel A: fused triple 1x1 conv (f, g, h) ----------------
// Grid: (1024, 4). Block 256 threads computes a 64(out-ch) x 64(spatial) tile
// for all three weight matrices, sharing one x tile. 4x4 register blocking.
__global__ __launch_bounds__(256) void conv3_kernel(
    const float* __restrict__ x,
    const float* __restrict__ wf, const float* __restrict__ bf,
    const float* __restrict__ wg, const float* __restrict__ bg,
    const float* __restrict__ wh, const float* __restrict__ bh,
    float* __restrict__ fx, float* __restrict__ gx, float* __restrict__ hx)
{
    __shared__ float Wl[3][64][17];   // +1 pad: conflict-free broadcast reads
    __shared__ float Xs[16][64];      // stride 64 keeps float4 16B-aligned

    const int tid = threadIdx.x;
    const int tx  = tid & 15;
    const int ty  = tid >> 4;
    const int b   = blockIdx.x >> 6;           // batch
    const int s0  = (blockIdx.x & 63) << 6;    // spatial tile base
    const int o0  = blockIdx.y << 6;           // out-channel tile base

    const float* Wm[3] = {wf, wg, wh};
    const float* Bm[3] = {bf, bg, bh};
    float*       Pm[3] = {fx, gx, hx};

    float acc[3][4][4];
    #pragma unroll
    for (int m = 0; m < 3; ++m)
        #pragma unroll
        for (int r = 0; r < 4; ++r)
            #pragma unroll
            for (int c = 0; c < 4; ++c) acc[m][r][c] = 0.f;

    const int kw = tid & 15;        // k index for W loads (coalesced runs)
    const int ow = tid >> 4;        // o base for W loads
    const int kx = tid >> 4;        // k index for X loads
    const int sx = (tid & 15) << 2; // spatial offset for X loads

    for (int kb = 0; kb < CH; kb += 16) {
        #pragma unroll
        for (int m = 0; m < 3; ++m) {
            #pragma unroll
            for (int j = 0; j < 4; ++j) {
                int o = ow + (j << 4);
                Wl[m][o][kw] = Wm[m][(o0 + o) * CH + kb + kw];
            }
        }
        *(float4*)&Xs[kx][sx] =
            *(const float4*)(x + (size_t)((b * CH + kb + kx) * SPA) + s0 + sx);
        __syncthreads();

        #pragma unroll
        for (int k = 0; k < 16; ++k) {
            float4 xb = *(const float4*)&Xs[k][tx << 2];
            #pragma unroll
            for (int m = 0; m < 3; ++m) {
                #pragma unroll
                for (int r = 0; r < 4; ++r) {
                    float a = Wl[m][(ty << 2) + r][k];   // broadcast across tx
                    acc[m][r][0] += a * xb.x;
                    acc[m][r][1] += a * xb.y;
                    acc[m][r][2] += a * xb.z;
                    acc[m][r][3] += a * xb.w;
                }
            }
        }
        __syncthreads();
    }

    #pragma unroll
    for (int m = 0; m < 3; ++m) {
        #pragma unroll
        for (int r = 0; r < 4; ++r) {
            int o = o0 + (ty << 2) + r;
            float bias = Bm[m][o];
            float4 v;
            v.x = acc[m][r][0] + bias;
            v.y = acc[m][r][1] + bias;
            v.z = acc[m][r][2] + bias;
            v.w = acc[m][r][3] + bias;
            *(float4*)(Pm[m] + (size_t)((b * CH + o) * SPA) + s0 + (tx << 2)) = v;
        }
    }
}

// ---------------- Kernel B: per-(b,c) spatial attention ----------------
// One block per (b,c). S = F^T G, softmax rows, O = H @ A. All fp32 in LDS.
// Row stride 68 floats: 272B (16B-aligned for float4) and pads banks.
__global__ __launch_bounds__(256) void attn_kernel(
    const float* __restrict__ fx, const float* __restrict__ gx,
    const float* __restrict__ hx, float* __restrict__ ob)
{
    __shared__ float smem[3][64][68];   // [0]=F (later H), [1]=G, [2]=S/A
    __shared__ float rinv[64];

    const int tid = threadIdx.x;
    const int tx = tid & 15, ty = tid >> 4;
    const int bc = blockIdx.x;
    const float* Fp = fx + (size_t)bc * SPA;
    const float* Gp = gx + (size_t)bc * SPA;
    const float* Hp = hx + (size_t)bc * SPA;
    float*       Op = ob + (size_t)bc * SPA;

    #pragma unroll
    for (int p = 0; p < 4; ++p) {
        int fi = (p << 8) + tid;
        int h = fi >> 4, w4 = (fi & 15) << 2;
        *(float4*)&smem[0][h][w4] = *(const float4*)(Fp + h * 64 + w4);
        *(float4*)&smem[1][h][w4] = *(const float4*)(Gp + h * 64 + w4);
    }
    __syncthreads();

    // S[w][v] = sum_h F[h][w] * G[h][v]
    const int w0 = ty << 2, v0 = tx << 2;
    float sa[4][4];
    #pragma unroll
    for (int r = 0; r < 4; ++r)
        #pragma unroll
        for (int c = 0; c < 4; ++c) sa[r][c] = 0.f;

    for (int h = 0; h < 64; ++h) {
        float4 a  = *(const float4*)&smem[0][h][w0];
        float4 g4 = *(const float4*)&smem[1][h][v0];
        #pragma unroll
        for (int r = 0; r < 4; ++r) {
            float av = (r == 0) ? a.x : (r == 1) ? a.y : (r == 2) ? a.z : a.w;
            sa[r][0] += av * g4.x;
            sa[r][1] += av * g4.y;
            sa[r][2] += av * g4.z;
            sa[r][3] += av * g4.w;
        }
    }
    #pragma unroll
    for (int r = 0; r < 4; ++r) {
        float4 v = {sa[r][0], sa[r][1], sa[r][2], sa[r][3]};
        *(float4*)&smem[2][w0 + r][v0] = v;
    }
    __syncthreads();

    // Row softmax (staggered column scan -> conflict-free)
    if (tid < 64) {
        float m = -INFINITY;
        for (int i = 0; i < 64; ++i) {
            int v = (i + tid) & 63;
            m = fmaxf(m, smem[2][tid][v]);
        }
        float s = 0.f;
        for (int i = 0; i < 64; ++i) {
            int v = (i + tid) & 63;
            float e = __expf(smem[2][tid][v] - m);
            smem[2][tid][v] = e;
            s += e;
        }
        rinv[tid] = 1.f / s;
    }
    __syncthreads();

    // Load H into F's slot (F dead), normalize A
    #pragma unroll
    for (int p = 0; p < 4; ++p) {
        int fi = (p << 8) + tid;
        int h = fi >> 4, w4 = (fi & 15) << 2;
        *(float4*)&smem[0][h][w4] = *(const float4*)(Hp + h * 64 + w4);
    }
    {
        int r = tid >> 2, c0 = (tid & 3) << 4;
        float riv = rinv[r];
        #pragma unroll
        for (int i = 0; i < 16; ++i) smem[2][r][c0 + i] *= riv;
    }
    __syncthreads();

    // O[h][v] = sum_w H[h][w] * A[w][v]
    const int h0 = ty << 2;
    float oa[4][4];
    #pragma unroll
    for (int r = 0; r < 4; ++r)
        #pragma unroll
        for (int c = 0; c < 4; ++c) oa[r][c] = 0.f;

    for (int w = 0; w < 64; ++w) {
        float4 av = *(const float4*)&smem[2][w][v0];
        #pragma unroll
        for (int r = 0; r < 4; ++r) {
            float hv = smem[0][h0 + r][w];   // 2-way max -> free
            oa[r][0] += hv * av.x;
            oa[r][1] += hv * av.y;
            oa[r][2] += hv * av.z;
            oa[r][3] += hv * av.w;
        }
    }
    #pragma unroll
    for (int r = 0; r < 4; ++r) {
        float4 v = {oa[r][0], oa[r][1], oa[r][2], oa[r][3]};
        *(float4*)(Op + (h0 + r) * 64 + v0) = v;
    }
}

// ---------------- Kernel C: final 1x1 conv ----------------
__global__ __launch_bounds__(256) void conv1_kernel(
    const float* __restrict__ xin,
    const float* __restrict__ wv, const float* __restrict__ bv,
    float* __restrict__ out)
{
    __shared__ float Wl[64][17];
    __shared__ float Xs[16][64];

    const int tid = threadIdx.x;
    const int tx  = tid & 15;
    const int ty  = tid >> 4;
    const int b   = blockIdx.x >> 6;
    const int s0  = (blockIdx.x & 63) << 6;
    const int o0  = blockIdx.y << 6;

    float acc[4][4];
    #pragma unroll
    for (int r = 0; r < 4; ++r)
        #pragma unroll
        for (int c = 0; c < 4; ++c) acc[r][c] = 0.f;

    const int kw = tid & 15;
    const int ow = tid >> 4;
    const int kx = tid >> 4;
    const int sx = (tid & 15) << 2;

    for (int kb = 0; kb < CH; kb += 16) {
        #pragma unroll
        for (int j = 0; j < 4; ++j) {
            int o = ow + (j << 4);
            Wl[o][kw] = wv[(o0 + o) * CH + kb + kw];
        }
        *(float4*)&Xs[kx][sx] =
            *(const float4*)(xin + (size_t)((b * CH + kb + kx) * SPA) + s0 + sx);
        __syncthreads();

        #pragma unroll
        for (int k = 0; k < 16; ++k) {
            float4 xb = *(const float4*)&Xs[k][tx << 2];
            #pragma unroll
            for (int r = 0; r < 4; ++r) {
                float a = Wl[(ty << 2) + r][k];
                acc[r][0] += a * xb.x;
                acc[r][1] += a * xb.y;
                acc[r][2] += a * xb.z;
                acc[r][3] += a * xb.w;
            }
        }
        __syncthreads();
    }

    #pragma unroll
    for (int r = 0; r < 4; ++r) {
        int o = o0 + (ty << 2) + r;
        float bias = bv[o];
        float4 v;
        v.x = acc[r][0] + bias;
        v.y = acc[r][1] + bias;
        v.z = acc[r][2] + bias;
        v.w = acc[r][3] + bias;
        *(float4*)(out + (size_t)((b * CH + o) * SPA) + s0 + (tx << 2)) = v;
    }
}

extern "C" void kernel_launch(void* const* d_in, const int* in_sizes, int n_in,
                              void* d_out, int out_size, void* d_ws, size_t ws_size,
                              hipStream_t stream)
{
    const float* x  = (const float*)d_in[0];
    const float* wf = (const float*)d_in[1];
    const float* bf = (const float*)d_in[2];
    const float* wg = (const float*)d_in[3];
    const float* bg = (const float*)d_in[4];
    const float* wh = (const float*)d_in[5];
    const float* bh = (const float*)d_in[6];
    const float* wv = (const float*)d_in[7];
    const float* bv = (const float*)d_in[8];

    float* fx = (float*)d_ws;
    float* gx = fx + PLANE;
    float* hx = gx + PLANE;
    float* ob = fx;   // attention output aliases fx (per-block slice reuse is safe)

    dim3 blk(256);
    conv3_kernel<<<dim3(BB * 64, 4), blk, 0, stream>>>(
        x, wf, bf, wg, bg, wh, bh, fx, gx, hx);
    attn_kernel<<<dim3(BB * CH), blk, 0, stream>>>(fx, gx, hx, ob);
    conv1_kernel<<<dim3(BB * 64, 4), blk, 0, stream>>>(
        ob, wv, bv, (float*)d_out);
}

// Round 2
// 355.966 us; speedup vs baseline: 1.7949x; 1.7949x over previous
//
#include <hip/hip_runtime.h>
#include <math.h>

#define CH  256
#define SPA 4096
#define BB  16

typedef short bf16x8 __attribute__((ext_vector_type(8)));
typedef float f32x4  __attribute__((ext_vector_type(4)));
typedef unsigned short us4 __attribute__((ext_vector_type(4)));
typedef unsigned short us8 __attribute__((ext_vector_type(8)));

__device__ __forceinline__ unsigned short f2bf(float f) {
    union { float f; unsigned u; } v; v.f = f;
    unsigned r = v.u + 0x7FFF + ((v.u >> 16) & 1);   // RNE
    return (unsigned short)(r >> 16);
}
__device__ __forceinline__ float bf2f(unsigned short h) {
    union { unsigned u; float f; } v; v.u = ((unsigned)h) << 16;
    return v.f;
}

__device__ __forceinline__ void gload16(const void* g, void* l) {
    __builtin_amdgcn_global_load_lds(
        (const __attribute__((address_space(1))) unsigned int*)g,
        (__attribute__((address_space(3))) unsigned int*)l, 16, 0, 0);
}

// ---------- transpose + bf16 hi/lo split: src[b][r][s] f32 -> dst[b][s][r] bf16 ----------
template<bool LO>
__global__ __launch_bounds__(256) void transpose_split_kernel(
    const float* __restrict__ src, unsigned short* __restrict__ dh,
    unsigned short* __restrict__ dl)
{
    __shared__ float T[64][65];
    const int t  = threadIdx.x;
    const int b  = blockIdx.x >> 8;
    const int st = (blockIdx.x >> 2) & 63;
    const int rt = blockIdx.x & 3;
    const int s0 = st << 6, r0 = rt << 6;

    #pragma unroll
    for (int p = 0; p < 4; ++p) {
        int k = (t >> 4) + (p << 4);
        float4 v = *(const float4*)(src + (((size_t)((b << 8) + r0 + k)) << 12)
                                        + s0 + ((t & 15) << 2));
        T[k][((t & 15) << 2) + 0] = v.x;
        T[k][((t & 15) << 2) + 1] = v.y;
        T[k][((t & 15) << 2) + 2] = v.z;
        T[k][((t & 15) << 2) + 3] = v.w;
    }
    __syncthreads();

    const int s  = t >> 2;
    const int kg = (t & 3) << 4;
    const size_t obase = (((size_t)((b << 12) + s0 + s)) << 8) + r0 + kg;

    us8 h0, h1, l0, l1;
    #pragma unroll
    for (int i = 0; i < 16; ++i) {
        float f = T[kg + i][s];
        unsigned short hv = f2bf(f);
        if (i < 8) h0[i] = hv; else h1[i - 8] = hv;
        if (LO) {
            unsigned short lv = f2bf(f - bf2f(hv));
            if (i < 8) l0[i] = lv; else l1[i - 8] = lv;
        }
    }
    *(us8*)(dh + obase)     = h0;
    *(us8*)(dh + obase + 8) = h1;
    if (LO) {
        *(us8*)(dl + obase)     = l0;
        *(us8*)(dl + obase + 8) = l1;
    }
}

// ---------- weight hi/lo split: 4 matrices [o][k] f32 -> bf16 hi/lo planes ----------
__global__ __launch_bounds__(256) void wsplit_kernel(
    const float* __restrict__ w0, const float* __restrict__ w1,
    const float* __restrict__ w2, const float* __restrict__ w3,
    unsigned short* __restrict__ dh, unsigned short* __restrict__ dl)
{
    const int idx = blockIdx.x * 256 + threadIdx.x;   // 0..65535
    const float* ws[4] = {w0, w1, w2, w3};
    #pragma unroll
    for (int m = 0; m < 4; ++m) {
        float f = ws[m][idx];
        unsigned short h = f2bf(f);
        dh[m * 65536 + idx] = h;
        dl[m * 65536 + idx] = f2bf(f - bf2f(h));
    }
}

// ---------- MFMA GEMM conv: out[b][o][s] = sum_k W[o][k] * X[b][s][k] + bias[o] ----------
// X supplied transposed+split bf16 ([b][s][k]); W split bf16 ([o][k]).
// SPLIT: 3-MFMA hi/lo product (near-fp32). OUTBF16: round-store bf16 else f32.
template<bool SPLIT, bool OUTBF16>
__global__ __launch_bounds__(256) void gemm_conv_kernel(
    const unsigned short* __restrict__ xhp, const unsigned short* __restrict__ xlp,
    const unsigned short* __restrict__ whp, const unsigned short* __restrict__ wlp,
    const float* __restrict__ bias, void* __restrict__ outp)
{
    extern __shared__ unsigned short S[];
    unsigned short* sAh = S;
    unsigned short* sAl = S + (SPLIT ? 4096 : 0);
    unsigned short* sBh = S + (SPLIT ? 8192 : 4096);
    unsigned short* sBl = S + 12288;

    const int tid  = threadIdx.x;
    const int w    = tid >> 6, lane = tid & 63;
    const int quad = lane >> 4, li = lane & 15;
    const int wx   = w & 1,  wy = w >> 1;

    const int ot    = blockIdx.x & 1;
    const int stile = (blockIdx.x >> 1) & 31;
    const int b     = blockIdx.x >> 6;
    const int s0 = stile << 7, o0 = ot << 7;

    f32x4 acc[4][4];
    #pragma unroll
    for (int t = 0; t < 4; ++t)
        #pragma unroll
        for (int u = 0; u < 4; ++u) acc[t][u] = (f32x4){0.f, 0.f, 0.f, 0.f};

    const int rr = lane >> 2;         // row within 16-row staging group
    const int cc = (lane & 3) << 3;   // k offset (ushorts) within 32-k row

    for (int kb = 0; kb < CH; kb += 32) {
        __syncthreads();
        #pragma unroll
        for (int j = 0; j < 32; j += 16) {
            const int r   = (w << 5) + j + rr;
            const size_t ga = (((size_t)((b << 12) + s0 + r)) << 8) + kb + cc;
            const size_t gb = (((size_t)(o0 + r)) << 8) + kb + cc;
            const int    lo_ = ((w << 5) + j) * 32 + lane * 8;
            gload16(xhp + ga, sAh + lo_);
            gload16(whp + gb, sBh + lo_);
            if (SPLIT) {
                gload16(xlp + ga, sAl + lo_);
                gload16(wlp + gb, sBl + lo_);
            }
        }
        __syncthreads();

        bf16x8 ah[4], bh[4], al[4], bl[4];
        #pragma unroll
        for (int t = 0; t < 4; ++t) {
            const int ra = ((wy << 6) + (t << 4) + li) * 32 + (quad << 3);
            const int rb = ((wx << 6) + (t << 4) + li) * 32 + (quad << 3);
            ah[t] = *(const bf16x8*)(sAh + ra);
            bh[t] = *(const bf16x8*)(sBh + rb);
            if (SPLIT) {
                al[t] = *(const bf16x8*)(sAl + ra);
                bl[t] = *(const bf16x8*)(sBl + rb);
            }
        }
        #pragma unroll
        for (int t = 0; t < 4; ++t)
            #pragma unroll
            for (int u = 0; u < 4; ++u) {
                acc[t][u] = __builtin_amdgcn_mfma_f32_16x16x32_bf16(ah[t], bh[u], acc[t][u], 0, 0, 0);
                if (SPLIT) {
                    acc[t][u] = __builtin_amdgcn_mfma_f32_16x16x32_bf16(ah[t], bl[u], acc[t][u], 0, 0, 0);
                    acc[t][u] = __builtin_amdgcn_mfma_f32_16x16x32_bf16(al[t], bh[u], acc[t][u], 0, 0, 0);
                }
            }
    }

    // epilogue: D[row=quad*4+reg][col=li]; row -> s (4 consecutive), col -> o
    #pragma unroll
    for (int u = 0; u < 4; ++u) {
        const int o  = o0 + (wx << 6) + (u << 4) + li;
        const float bz = bias[o];
        #pragma unroll
        for (int t = 0; t < 4; ++t) {
            const int s = s0 + (wy << 6) + (t << 4) + (quad << 2);
            const size_t off = (((size_t)((b << 8) + o)) << 12) + s;
            f32x4 v = acc[t][u];
            if (OUTBF16) {
                unsigned short* ob = (unsigned short*)outp;
                us4 pv;
                pv[0] = f2bf(v[0] + bz); pv[1] = f2bf(v[1] + bz);
                pv[2] = f2bf(v[2] + bz); pv[3] = f2bf(v[3] + bz);
                *(us4*)(ob + off) = pv;
            } else {
                float* of = (float*)outp;
                float4 pv = {v[0] + bz, v[1] + bz, v[2] + bz, v[3] + bz};
                *(float4*)(of + off) = pv;
            }
        }
    }
}

// ---------------- per-(b,c) spatial attention (fp32 math, bf16 inputs) ----------------
__global__ __launch_bounds__(256) void attn_kernel(
    const unsigned short* __restrict__ fx, const unsigned short* __restrict__ gx,
    const unsigned short* __restrict__ hx, float* __restrict__ ob)
{
    __shared__ float smem[3][64][68];
    __shared__ float rinv[64];

    const int tid = threadIdx.x;
    const int tx = tid & 15, ty = tid >> 4;
    const int bc = blockIdx.x;
    const unsigned short* Fp = fx + (size_t)bc * SPA;
    const unsigned short* Gp = gx + (size_t)bc * SPA;
    const unsigned short* Hp = hx + (size_t)bc * SPA;
    float* Op = ob + (size_t)bc * SPA;

    #pragma unroll
    for (int p = 0; p < 4; ++p) {
        int fi = (p << 8) + tid;
        int h = fi >> 4, w4 = (fi & 15) << 2;
        us4 uf = *(const us4*)(Fp + h * 64 + w4);
        us4 ug = *(const us4*)(Gp + h * 64 + w4);
        #pragma unroll
        for (int i = 0; i < 4; ++i) {
            smem[0][h][w4 + i] = bf2f(uf[i]);
            smem[1][h][w4 + i] = bf2f(ug[i]);
        }
    }
    __syncthreads();

    const int w0 = ty << 2, v0 = tx << 2;
    float sa[4][4];
    #pragma unroll
    for (int r = 0; r < 4; ++r)
        #pragma unroll
        for (int c = 0; c < 4; ++c) sa[r][c] = 0.f;

    for (int h = 0; h < 64; ++h) {
        float4 a  = *(const float4*)&smem[0][h][w0];
        float4 g4 = *(const float4*)&smem[1][h][v0];
        #pragma unroll
        for (int r = 0; r < 4; ++r) {
            float av = (r == 0) ? a.x : (r == 1) ? a.y : (r == 2) ? a.z : a.w;
            sa[r][0] += av * g4.x;
            sa[r][1] += av * g4.y;
            sa[r][2] += av * g4.z;
            sa[r][3] += av * g4.w;
        }
    }
    #pragma unroll
    for (int r = 0; r < 4; ++r) {
        float4 v = {sa[r][0], sa[r][1], sa[r][2], sa[r][3]};
        *(float4*)&smem[2][w0 + r][v0] = v;
    }
    __syncthreads();

    if (tid < 64) {
        float m = -INFINITY;
        for (int i = 0; i < 64; ++i) {
            int v = (i + tid) & 63;
            m = fmaxf(m, smem[2][tid][v]);
        }
        float s = 0.f;
        for (int i = 0; i < 64; ++i) {
            int v = (i + tid) & 63;
            float e = __expf(smem[2][tid][v] - m);
            smem[2][tid][v] = e;
            s += e;
        }
        rinv[tid] = 1.f / s;
    }
    __syncthreads();

    #pragma unroll
    for (int p = 0; p < 4; ++p) {
        int fi = (p << 8) + tid;
        int h = fi >> 4, w4 = (fi & 15) << 2;
        us4 uh = *(const us4*)(Hp + h * 64 + w4);
        #pragma unroll
        for (int i = 0; i < 4; ++i) smem[0][h][w4 + i] = bf2f(uh[i]);
    }
    {
        int r = tid >> 2, c0 = (tid & 3) << 4;
        float riv = rinv[r];
        #pragma unroll
        for (int i = 0; i < 16; ++i) smem[2][r][c0 + i] *= riv;
    }
    __syncthreads();

    const int h0 = ty << 2;
    float oa[4][4];
    #pragma unroll
    for (int r = 0; r < 4; ++r)
        #pragma unroll
        for (int c = 0; c < 4; ++c) oa[r][c] = 0.f;

    for (int w = 0; w < 64; ++w) {
        float4 av = *(const float4*)&smem[2][w][v0];
        #pragma unroll
        for (int r = 0; r < 4; ++r) {
            float hv = smem[0][h0 + r][w];
            oa[r][0] += hv * av.x;
            oa[r][1] += hv * av.y;
            oa[r][2] += hv * av.z;
            oa[r][3] += hv * av.w;
        }
    }
    #pragma unroll
    for (int r = 0; r < 4; ++r) {
        float4 v = {oa[r][0], oa[r][1], oa[r][2], oa[r][3]};
        *(float4*)(Op + (h0 + r) * 64 + v0) = v;
    }
}

extern "C" void kernel_launch(void* const* d_in, const int* in_sizes, int n_in,
                              void* d_out, int out_size, void* d_ws, size_t ws_size,
                              hipStream_t stream)
{
    const float* x  = (const float*)d_in[0];
    const float* wf = (const float*)d_in[1];
    const float* bf = (const float*)d_in[2];
    const float* wg = (const float*)d_in[3];
    const float* bg = (const float*)d_in[4];
    const float* wh = (const float*)d_in[5];
    const float* bh = (const float*)d_in[6];
    const float* wv = (const float*)d_in[7];
    const float* bv = (const float*)d_in[8];

    char* base = (char*)d_ws;
    const size_t MB = 1ull << 20;
    unsigned short* xh  = (unsigned short*)base;              // [0,32) MiB
    unsigned short* xl  = (unsigned short*)(base + 32 * MB);  // [32,64)
    unsigned short* fxb = (unsigned short*)(base + 64 * MB);  // [64,96)
    unsigned short* gxb = (unsigned short*)(base + 96 * MB);  // [96,128)
    unsigned short* hxb = (unsigned short*)(base + 128 * MB); // [128,160)
    float*          ob  = (float*)base;                       // [0,64) after xh/xl dead
    unsigned short* obT = fxb;                                // [64,96) after fxb dead
    unsigned short* wsh = (unsigned short*)(base + 160 * MB); // 512 KB
    unsigned short* wsl = wsh + 4 * 65536;                    // 512 KB

    dim3 blk(256);
    transpose_split_kernel<true><<<4096, blk, 0, stream>>>(x, xh, xl);
    wsplit_kernel<<<256, blk, 0, stream>>>(wf, wg, wh, wv, wsh, wsl);

    gemm_conv_kernel<true,  true ><<<1024, blk, 32768, stream>>>(xh, xl, wsh,          wsl,          bf, fxb);
    gemm_conv_kernel<true,  true ><<<1024, blk, 32768, stream>>>(xh, xl, wsh + 65536,  wsl + 65536,  bg, gxb);
    gemm_conv_kernel<false, true ><<<1024, blk, 16384, stream>>>(xh, xl, wsh + 131072, wsl,          bh, hxb);

    attn_kernel<<<4096, blk, 0, stream>>>(fxb, gxb, hxb, ob);

    transpose_split_kernel<false><<<4096, blk, 0, stream>>>(ob, obT, nullptr);

    gemm_conv_kernel<false, false><<<1024, blk, 16384, stream>>>(obT, nullptr, wsh + 196608, nullptr, bv, (float*)d_out);
}

// Round 3
// 256.040 us; speedup vs baseline: 2.4955x; 1.3903x over previous
//
#include <hip/hip_runtime.h>
#include <math.h>

#define CH  256
#define SPA 4096
#define BB  16
#define PLANE 16777216   // 16*256*4096 elements per tensor

typedef _Float16 f16x8 __attribute__((ext_vector_type(8)));
typedef _Float16 f16x4 __attribute__((ext_vector_type(4)));
typedef float    f32x4 __attribute__((ext_vector_type(4)));

__device__ __forceinline__ void gload16(const void* g, void* l) {
    __builtin_amdgcn_global_load_lds(
        (const __attribute__((address_space(1))) unsigned int*)g,
        (__attribute__((address_space(3))) unsigned int*)l, 16, 0, 0);
}

// ---------- x transpose + fp16 cvt: src[b][r][s] f32 -> dst[b][s][r] fp16 ----------
__global__ __launch_bounds__(256) void xpose_kernel(
    const float* __restrict__ src, _Float16* __restrict__ dst)
{
    __shared__ float T[64][65];
    const int t  = threadIdx.x;
    const int b  = blockIdx.x >> 8;
    const int st = (blockIdx.x >> 2) & 63;
    const int rt = blockIdx.x & 3;
    const int s0 = st << 6, r0 = rt << 6;

    #pragma unroll
    for (int p = 0; p < 4; ++p) {
        int k = (t >> 4) + (p << 4);
        float4 v = *(const float4*)(src + (((size_t)((b << 8) + r0 + k)) << 12)
                                        + s0 + ((t & 15) << 2));
        T[k][((t & 15) << 2) + 0] = v.x;
        T[k][((t & 15) << 2) + 1] = v.y;
        T[k][((t & 15) << 2) + 2] = v.z;
        T[k][((t & 15) << 2) + 3] = v.w;
    }
    __syncthreads();

    const int s  = t >> 2;
    const int kg = (t & 3) << 4;
    const size_t obase = (((size_t)((b << 12) + s0 + s)) << 8) + r0 + kg;

    f16x8 h0, h1;
    #pragma unroll
    for (int i = 0; i < 16; ++i) {
        _Float16 hv = (_Float16)T[kg + i][s];
        if (i < 8) h0[i] = hv; else h1[i - 8] = hv;
    }
    *(f16x8*)(dst + obase)     = h0;
    *(f16x8*)(dst + obase + 8) = h1;
}

// ---------- channel transpose fp16: src[b][c][s] -> dst[b][s][c] ----------
__global__ __launch_bounds__(256) void cpose_kernel(
    const _Float16* __restrict__ src, _Float16* __restrict__ dst)
{
    __shared__ _Float16 T[64][68];
    const int t  = threadIdx.x;
    const int b  = blockIdx.x >> 8;
    const int st = (blockIdx.x >> 2) & 63;
    const int ct = blockIdx.x & 3;
    const int s0 = st << 6, c0 = ct << 6;

    #pragma unroll
    for (int p = 0; p < 4; ++p) {
        int fi = (p << 8) + t;
        int r = fi >> 4, s4 = (fi & 15) << 2;
        f16x4 v = *(const f16x4*)(src + (((size_t)((b << 8) + c0 + r)) << 12) + s0 + s4);
        *(f16x4*)&T[r][s4] = v;
    }
    __syncthreads();

    const int s  = t >> 2;
    const int cg = (t & 3) << 4;
    f16x8 h0, h1;
    #pragma unroll
    for (int i = 0; i < 16; ++i) {
        _Float16 hv = T[cg + i][s];
        if (i < 8) h0[i] = hv; else h1[i - 8] = hv;
    }
    const size_t obase = (((size_t)((b << 12) + s0 + s)) << 8) + c0 + cg;
    *(f16x8*)(dst + obase)     = h0;
    *(f16x8*)(dst + obase + 8) = h1;
}

// ---------- weight cvt: 4 matrices [o][k] f32 -> fp16 ----------
__global__ __launch_bounds__(256) void wcvt_kernel(
    const float* __restrict__ w0, const float* __restrict__ w1,
    const float* __restrict__ w2, const float* __restrict__ w3,
    _Float16* __restrict__ dst)
{
    const int idx = blockIdx.x * 256 + threadIdx.x;
    dst[idx]             = (_Float16)w0[idx];
    dst[65536 + idx]     = (_Float16)w1[idx];
    dst[131072 + idx]    = (_Float16)w2[idx];
    dst[196608 + idx]    = (_Float16)w3[idx];
}

// ---------- fp16 MFMA GEMM conv: out[b][o][s] = W[o][:].X[b][s][:] + bias ----------
template<bool OUTF16>
__global__ __launch_bounds__(256) void gemm16_kernel(
    const _Float16* __restrict__ xT, const _Float16* __restrict__ wc,
    const float* __restrict__ bias0, const float* __restrict__ bias1,
    const float* __restrict__ bias2, void* __restrict__ outp)
{
    __shared__ _Float16 S[8192];
    _Float16* sA = S;
    _Float16* sB = S + 4096;

    const int m = blockIdx.y;
    const _Float16* wp = wc + m * 65536;
    const float* bias = (m == 0) ? bias0 : ((m == 1) ? bias1 : bias2);

    const int tid = threadIdx.x;
    const int w = tid >> 6, lane = tid & 63, quad = lane >> 4, li = lane & 15;
    const int wx = w & 1, wy = w >> 1;
    const int ot    = blockIdx.x & 1;
    const int stile = (blockIdx.x >> 1) & 31;
    const int b     = blockIdx.x >> 6;
    const int s0 = stile << 7, o0 = ot << 7;

    f32x4 acc[4][4];
    #pragma unroll
    for (int t2 = 0; t2 < 4; ++t2)
        #pragma unroll
        for (int u = 0; u < 4; ++u) acc[t2][u] = (f32x4){0.f, 0.f, 0.f, 0.f};

    const int rr = lane >> 2, cc = (lane & 3) << 3;

    for (int kb = 0; kb < CH; kb += 32) {
        __syncthreads();
        #pragma unroll
        for (int j = 0; j < 32; j += 16) {
            const int r = (w << 5) + j + rr;
            const size_t ga = (((size_t)((b << 12) + s0 + r)) << 8) + kb + cc;
            const size_t gb = ((size_t)(o0 + r) << 8) + kb + cc;
            const int lo_ = ((w << 5) + j) * 32 + lane * 8;
            gload16(xT + ga, sA + lo_);
            gload16(wp + gb, sB + lo_);
        }
        __syncthreads();

        f16x8 a[4], bfr[4];
        #pragma unroll
        for (int t2 = 0; t2 < 4; ++t2) {
            a[t2]   = *(const f16x8*)(sA + ((wy << 6) + (t2 << 4) + li) * 32 + (quad << 3));
            bfr[t2] = *(const f16x8*)(sB + ((wx << 6) + (t2 << 4) + li) * 32 + (quad << 3));
        }
        #pragma unroll
        for (int t2 = 0; t2 < 4; ++t2)
            #pragma unroll
            for (int u = 0; u < 4; ++u)
                acc[t2][u] = __builtin_amdgcn_mfma_f32_16x16x32_f16(a[t2], bfr[u], acc[t2][u], 0, 0, 0);
    }

    #pragma unroll
    for (int u = 0; u < 4; ++u) {
        const int o = o0 + (wx << 6) + (u << 4) + li;
        const float bz = bias[o];
        #pragma unroll
        for (int t2 = 0; t2 < 4; ++t2) {
            const int s = s0 + (wy << 6) + (t2 << 4) + (quad << 2);
            const size_t off = (((size_t)((b << 8) + o)) << 12) + s;
            f32x4 v = acc[t2][u];
            if (OUTF16) {
                _Float16* ob = (_Float16*)outp + (size_t)m * PLANE;
                f16x4 pv;
                pv[0] = (_Float16)(v[0] + bz); pv[1] = (_Float16)(v[1] + bz);
                pv[2] = (_Float16)(v[2] + bz); pv[3] = (_Float16)(v[3] + bz);
                *(f16x4*)(ob + off) = pv;
            } else {
                float* of = (float*)outp;
                float4 pv = {v[0] + bz, v[1] + bz, v[2] + bz, v[3] + bz};
                *(float4*)(of + off) = pv;
            }
        }
    }
}

// ---------- MFMA attention: one block per (b,c) ----------
// S = F^T G via MFMA (operands transposed in LDS via MFMA x identity),
// row softmax, O = H . P via MFMA. All fp16 operands, fp32 accum.
__global__ __launch_bounds__(256) void attn_mfma_kernel(
    const _Float16* __restrict__ fx, const _Float16* __restrict__ gx,
    const _Float16* __restrict__ hx, _Float16* __restrict__ ob)
{
    __shared__ short lds_s[27136];          // 54272 B -> 3 blocks/CU
    _Float16* L = (_Float16*)lds_s;
    float* Sff = (float*)(lds_s + 18432);   // S fp32 [64][68]
    const int FT = 0, GT = 4608, HM = 9216, PT = 13824;  // pitch 72 fp16
    const int FR = 18432, GR = 13824;       // raw staging: FR aliases Sf, GR aliases Pt

    const int t = threadIdx.x;
    const int wave = t >> 6, lane = t & 63, q = lane >> 4, li = lane & 15;
    const int bc = blockIdx.x;
    const _Float16* Fp = fx + (size_t)bc * SPA;
    const _Float16* Gp = gx + (size_t)bc * SPA;
    const _Float16* Hp = hx + (size_t)bc * SPA;
    _Float16* Op = ob + (size_t)bc * SPA;

    // stage F,G,H (pitch-72 rows, b128 writes)
    #pragma unroll
    for (int p = 0; p < 2; ++p) {
        int ci = t + (p << 8);
        int h = ci >> 3, w8 = (ci & 7) << 3;
        f16x8 f  = *(const f16x8*)(Fp + h * 64 + w8);
        f16x8 g  = *(const f16x8*)(Gp + h * 64 + w8);
        f16x8 hh = *(const f16x8*)(Hp + h * 64 + w8);
        *(f16x8*)&L[FR + h * 72 + w8] = f;
        *(f16x8*)&L[GR + h * 72 + w8] = g;
        *(f16x8*)&L[HM + h * 72 + w8] = hh;
    }
    __syncthreads();

    // transpose F,G via MFMA x identity: D = A*I lands A in C-layout -> b64 stores
    {
        const int src = (wave < 2) ? FR : GR;
        const int dst = (wave < 2) ? FT : GT;
        const int mtb = (wave & 1) << 1;
        f16x8 id0, id1;
        #pragma unroll
        for (int j = 0; j < 8; ++j) {
            id0[j] = (_Float16)(((q << 3) + j == li)      ? 1.0f : 0.0f);
            id1[j] = (_Float16)(((q << 3) + j == li + 16) ? 1.0f : 0.0f);
        }
        #pragma unroll
        for (int mi = 0; mi < 2; ++mi) {
            const int mt = mtb + mi;
            f16x8 a0 = *(const f16x8*)&L[src + (mt * 16 + li) * 72 + (q << 3)];
            f16x8 a1 = *(const f16x8*)&L[src + (mt * 16 + li) * 72 + 32 + (q << 3)];
            #pragma unroll
            for (int nt = 0; nt < 4; ++nt) {
                f32x4 d = {0.f, 0.f, 0.f, 0.f};
                d = __builtin_amdgcn_mfma_f32_16x16x32_f16(
                        (nt < 2) ? a0 : a1, (nt & 1) ? id1 : id0, d, 0, 0, 0);
                f16x4 e;
                e[0] = (_Float16)d[0]; e[1] = (_Float16)d[1];
                e[2] = (_Float16)d[2]; e[3] = (_Float16)d[3];
                *(f16x4*)&L[dst + (nt * 16 + li) * 72 + mt * 16 + (q << 2)] = e;
            }
        }
    }
    __syncthreads();

    // S-GEMM: wave computes S rows [wave*16, wave*16+16)
    {
        f16x8 a0 = *(const f16x8*)&L[FT + (wave * 16 + li) * 72 + (q << 3)];
        f16x8 a1 = *(const f16x8*)&L[FT + (wave * 16 + li) * 72 + 32 + (q << 3)];
        f32x4 s_[4];
        #pragma unroll
        for (int nt = 0; nt < 4; ++nt) {
            f16x8 b0 = *(const f16x8*)&L[GT + (nt * 16 + li) * 72 + (q << 3)];
            f16x8 b1 = *(const f16x8*)&L[GT + (nt * 16 + li) * 72 + 32 + (q << 3)];
            f32x4 acc = {0.f, 0.f, 0.f, 0.f};
            acc = __builtin_amdgcn_mfma_f32_16x16x32_f16(a0, b0, acc, 0, 0, 0);
            acc = __builtin_amdgcn_mfma_f32_16x16x32_f16(a1, b1, acc, 0, 0, 0);
            s_[nt] = acc;
        }
        #pragma unroll
        for (int nt = 0; nt < 4; ++nt)
            #pragma unroll
            for (int r = 0; r < 4; ++r)
                Sff[(wave * 16 + (q << 2) + r) * 68 + nt * 16 + li] = s_[nt][r];
    }
    __syncthreads();

    // softmax rows of S; write P^T (chunk-XOR-swizzled) as fp16
    {
        const int row = t >> 2, c0s = (t & 3) << 4;
        float e[16];
        float mx = -1e30f;
        #pragma unroll
        for (int i = 0; i < 16; ++i) {
            e[i] = Sff[row * 68 + c0s + i];
            mx = fmaxf(mx, e[i]);
        }
        mx = fmaxf(mx, __shfl_xor(mx, 1));
        mx = fmaxf(mx, __shfl_xor(mx, 2));
        float sm = 0.f;
        #pragma unroll
        for (int i = 0; i < 16; ++i) { e[i] = __expf(e[i] - mx); sm += e[i]; }
        sm += __shfl_xor(sm, 1);
        sm += __shfl_xor(sm, 2);
        const float ri = 1.f / sm;
        #pragma unroll
        for (int i = 0; i < 16; ++i) {
            const int v = c0s + i;
            const int col = row ^ (((v >> 3) & 7) << 3);
            L[PT + v * 72 + col] = (_Float16)(e[i] * ri);
        }
    }
    __syncthreads();

    // O-GEMM: O[h][v] = sum_w H[h][w] P[w][v]
    {
        f16x8 a0 = *(const f16x8*)&L[HM + (wave * 16 + li) * 72 + (q << 3)];
        f16x8 a1 = *(const f16x8*)&L[HM + (wave * 16 + li) * 72 + 32 + (q << 3)];
        #pragma unroll
        for (int nt = 0; nt < 4; ++nt) {
            const int v  = nt * 16 + li;
            const int sw = ((v >> 3) & 7) << 3;
            f16x8 b0 = *(const f16x8*)&L[PT + v * 72 + ((q << 3) ^ sw)];
            f16x8 b1 = *(const f16x8*)&L[PT + v * 72 + ((32 + (q << 3)) ^ sw)];
            f32x4 acc = {0.f, 0.f, 0.f, 0.f};
            acc = __builtin_amdgcn_mfma_f32_16x16x32_f16(a0, b0, acc, 0, 0, 0);
            acc = __builtin_amdgcn_mfma_f32_16x16x32_f16(a1, b1, acc, 0, 0, 0);
            #pragma unroll
            for (int r = 0; r < 4; ++r)
                Op[(wave * 16 + (q << 2) + r) * 64 + v] = (_Float16)acc[r];
        }
    }
}

extern "C" void kernel_launch(void* const* d_in, const int* in_sizes, int n_in,
                              void* d_out, int out_size, void* d_ws, size_t ws_size,
                              hipStream_t stream)
{
    const float* x  = (const float*)d_in[0];
    const float* wf = (const float*)d_in[1];
    const float* bf = (const float*)d_in[2];
    const float* wg = (const float*)d_in[3];
    const float* bg = (const float*)d_in[4];
    const float* wh = (const float*)d_in[5];
    const float* bh = (const float*)d_in[6];
    const float* wv = (const float*)d_in[7];
    const float* bv = (const float*)d_in[8];

    char* base = (char*)d_ws;
    const size_t MB = 1ull << 20;
    _Float16* xT  = (_Float16*)base;               // [0,32)  MiB
    _Float16* fxb = (_Float16*)(base + 32 * MB);   // [32,64)
    _Float16* gxb = (_Float16*)(base + 64 * MB);   // [64,96)
    _Float16* hxb = (_Float16*)(base + 96 * MB);   // [96,128)
    _Float16* ob  = (_Float16*)(base + 128 * MB);  // [128,160)
    _Float16* obT = (_Float16*)base;               // [0,32) — xT dead after convs
    _Float16* wc  = (_Float16*)(base + 160 * MB);  // 512 KB

    dim3 blk(256);
    xpose_kernel<<<4096, blk, 0, stream>>>(x, xT);
    wcvt_kernel<<<256, blk, 0, stream>>>(wf, wg, wh, wv, wc);

    gemm16_kernel<true><<<dim3(1024, 3), blk, 0, stream>>>(
        xT, wc, bf, bg, bh, fxb);

    attn_mfma_kernel<<<4096, blk, 0, stream>>>(fxb, gxb, hxb, ob);

    cpose_kernel<<<4096, blk, 0, stream>>>(ob, obT);

    gemm16_kernel<false><<<dim3(1024, 1), blk, 0, stream>>>(
        obT, wc + 196608, bv, bv, bv, d_out);
}